// Round 8
// baseline (372.810 us; speedup 1.0000x reference)
//
#include <hip/hip_runtime.h>

#define BATCH 512
#define TT    1024
#define NST   64
#define NSYM  32
#define LN2F  0.69314718055994530942f

typedef _Float16 half2v __attribute__((ext_vector_type(2)));

// Raw barrier: LDS-ordering only (lgkmcnt), NO vmcnt drain -- producer's
// in-flight global E loads survive across the barrier (T4 pattern).
#define BAR() do {                                            \
    asm volatile("s_waitcnt lgkmcnt(0)" ::: "memory");        \
    __builtin_amdgcn_s_barrier();                             \
    asm volatile("" ::: "memory");                            \
} while (0)

// ---------------------------------------------------------------------------
// Wave64 sum reduction on the VALU only (DPP row ops). Total -> lane 63 -> SGPR.
// ---------------------------------------------------------------------------
template <int CTRL>
__device__ __forceinline__ float dpp_add(float x) {
    int y = __builtin_amdgcn_update_dpp(0, __float_as_int(x), CTRL, 0xf, 0xf, true);
    return x + __int_as_float(y);
}
__device__ __forceinline__ float wave64_sum_sgpr(float x) {
    x = dpp_add<0x111>(x);   // row_shr:1
    x = dpp_add<0x112>(x);   // row_shr:2
    x = dpp_add<0x114>(x);   // row_shr:4
    x = dpp_add<0x118>(x);   // row_shr:8
    x = dpp_add<0x142>(x);   // row_bcast:15
    x = dpp_add<0x143>(x);   // row_bcast:31 -> lane63 = total
    return __int_as_float(__builtin_amdgcn_readlane(__float_as_int(x), 63));
}

// ---------------------------------------------------------------------------
// Prep: softmax(transition) -> ws[0..4095]   (A[i][j], row-major)
//       softmax(emission)   -> ws[4096..6143] (B[n][s], row-major)
//       softmax(init)       -> ws[6144..6207] (I[n])
// ---------------------------------------------------------------------------
__global__ __launch_bounds__(64) void hmm_prep(
    const float* __restrict__ em, const float* __restrict__ tr,
    const float* __restrict__ ini, float* __restrict__ ws)
{
    const int n = threadIdx.x;

    {
        float a[64];
        float m = -1e30f;
        #pragma unroll
        for (int j = 0; j < 64; ++j) { a[j] = tr[n * 64 + j]; m = fmaxf(m, a[j]); }
        float s = 0.f;
        #pragma unroll
        for (int j = 0; j < 64; ++j) { a[j] = __expf(a[j] - m); s += a[j]; }
        const float inv = 1.f / s;
        #pragma unroll
        for (int j = 0; j < 64; ++j) ws[n * 64 + j] = a[j] * inv;
    }
    {
        float bv[32];
        float m = -1e30f;
        #pragma unroll
        for (int j = 0; j < 32; ++j) { bv[j] = em[n * 32 + j]; m = fmaxf(m, bv[j]); }
        float s = 0.f;
        #pragma unroll
        for (int j = 0; j < 32; ++j) { bv[j] = __expf(bv[j] - m); s += bv[j]; }
        const float inv = 1.f / s;
        #pragma unroll
        for (int j = 0; j < 32; ++j) ws[4096 + n * 32 + j] = bv[j] * inv;
    }
    {
        float v = ini[n];
        float m = v;
        #pragma unroll
        for (int off = 32; off; off >>= 1) m = fmaxf(m, __shfl_xor(m, off, 64));
        const float e = __expf(v - m);
        float s = e;
        #pragma unroll
        for (int off = 32; off; off >>= 1) s += __shfl_xor(s, off, 64);
        ws[6144 + n] = e / s;
    }
}

// ---------------------------------------------------------------------------
// Emission pass: E[b][t][n] = dot(B[n,:], x[b,t,:]) stored INTO d_out's fwd
// slots (op[t*65 + n]).  The scan reads E row t before the consumer wave
// overwrites row t (writes lag reads by >= 2 groups), so no collision.
// ---------------------------------------------------------------------------
__global__ __launch_bounds__(256) void hmm_emit(
    const float* __restrict__ inputs, const float* __restrict__ ws,
    float* __restrict__ out)
{
    const int b    = blockIdx.x >> 5;
    const int chk  = blockIdx.x & 31;    // 32 t-rows per block
    const int tid  = threadIdx.x;
    const int lane = tid & 63;
    const int w    = tid >> 6;

    __shared__ float xs[32 * 32];
    const float* __restrict__ xp = inputs + ((size_t)b * TT + (size_t)chk * 32) * NSYM;
    reinterpret_cast<float4*>(xs)[tid] = reinterpret_cast<const float4*>(xp)[tid];

    float Brow[32];
    {
        const float4* B4 = reinterpret_cast<const float4*>(ws + 4096 + lane * 32);
        #pragma unroll
        for (int i = 0; i < 8; ++i) {
            float4 v = B4[i];
            Brow[4*i+0] = v.x; Brow[4*i+1] = v.y;
            Brow[4*i+2] = v.z; Brow[4*i+3] = v.w;
        }
    }
    __syncthreads();

    float* __restrict__ op = out + ((size_t)b * TT + (size_t)chk * 32) * 65;
    #pragma unroll
    for (int r = 0; r < 8; ++r) {
        const int trow = w * 8 + r;
        const float4* x4 = reinterpret_cast<const float4*>(xs + trow * 32);
        float e0 = 0.f, e1 = 0.f, e2 = 0.f, e3 = 0.f;
        #pragma unroll
        for (int i = 0; i < 8; ++i) {
            float4 v = x4[i];
            e0 = fmaf(Brow[4*i+0], v.x, e0);
            e1 = fmaf(Brow[4*i+1], v.y, e1);
            e2 = fmaf(Brow[4*i+2], v.z, e2);
            e3 = fmaf(Brow[4*i+3], v.w, e3);
        }
        op[(size_t)trow * 65 + lane] = (e0 + e1) + (e2 + e3);
    }
}

// ---------------------------------------------------------------------------
// Scan: 1 chain per block, 2 waves = producer + consumer (role split).
//  PRODUCER (wave 0): recurrence ONLY.  h_t = (E_t * sc_t) o (A^T h_{t-1})
//    via 32x v_readlane + 32x v_dot2_f32_f16; sc_t = exact power of 2 from the
//    stale exponent of h_{t-1}[0] (SALU).  Writes h rows to LDS, refills the
//    8-deep E register ring (1 global load/step, stays in flight across the
//    raw barrier).  NO reduction, NO log/rcp, NO output stores.
//  CONSUMER (wave 1): one group (8 rows) behind.  Recomputes sc/Esum from the
//    exact h bits in LDS (pure function -> identical), does DPP sum, rcp, log,
//    and both output stores.  Has ~2.5x slack vs producer.
//  Sync: raw s_barrier + lgkmcnt(0) every 8 steps; Hbuf double-buffered.
// ---------------------------------------------------------------------------
__global__ __launch_bounds__(128, 1) void hmm_scan(
    const float* __restrict__ ws, float* __restrict__ out)
{
    const int w    = threadIdx.x >> 6;
    const int lane = threadIdx.x & 63;
    const int b    = blockIdx.x;

    __shared__ float Hbuf[2][8][64];

    float* __restrict__ op = out + (size_t)b * (TT * 65);

    // ---- producer state ----
    int   apk[32];
    float eR[8];
    float hprev = 0.f;

    if (w == 0) {
        #pragma unroll
        for (int d = 0; d < 32; ++d) {
            const float a0 = ws[(2 * d)     * 64 + lane];
            const float a1 = ws[(2 * d + 1) * 64 + lane];
            apk[d] = __builtin_bit_cast(int, __builtin_amdgcn_cvt_pkrtz(a0, a1));
        }
        #pragma unroll
        for (int d = 0; d < 32; ++d) asm volatile("" : "+v"(apk[d]));
        const float Iv_l = ws[6144 + lane];
        #pragma unroll
        for (int k = 0; k < 8; ++k) eR[k] = op[k * 65 + lane];
        // t = 0 peel: h0 = E0 o I (no matvec, sc = 1)
        hprev = eR[0] * Iv_l;
        Hbuf[0][0][lane] = hprev;
        eR[0] = op[8 * 65 + lane];
    }

    // ---- consumer state ----
    int Esum = 0, exPrevC = 127;   // exPrevC=127 -> row 0 adds 0

    // producer body for one step (j = ring slot, compile-time)
    auto pbody = [&](int j, const float* enext, float* hrow, bool refill) {
        // scale feedback from h_{t-1}[0] (SALU; resolves under the matvec)
        const unsigned bits = __builtin_amdgcn_readfirstlane(__float_as_uint(hprev));
        int ex = (int)((bits >> 23) & 255u);
        ex = ex < 1 ? 1 : (ex > 253 ? 253 : ex);
        const float sc = __uint_as_float((unsigned)(254 - ex) << 23);   // 2^(127-ex)
        const float eRs = eR[j] * sc;

        // pack (h[2i], h[2i+1]) into half2 in even lanes
        const int hnb = __builtin_amdgcn_update_dpp(
            0, __float_as_int(hprev), 0x101, 0xf, 0xf, true);   // row_shl:1
        const int hpki = __builtin_bit_cast(int,
            __builtin_amdgcn_cvt_pkrtz(hprev, __int_as_float(hnb)));

        float r0 = 0.f, r1 = 0.f, r2 = 0.f, r3 = 0.f;
        float r4 = 0.f, r5 = 0.f, r6 = 0.f, r7 = 0.f;
        #pragma unroll
        for (int d = 0; d < 4; ++d) {
            const int h0 = __builtin_amdgcn_readlane(hpki, 16 * d + 0);
            const int h1 = __builtin_amdgcn_readlane(hpki, 16 * d + 2);
            const int h2 = __builtin_amdgcn_readlane(hpki, 16 * d + 4);
            const int h3 = __builtin_amdgcn_readlane(hpki, 16 * d + 6);
            const int h4 = __builtin_amdgcn_readlane(hpki, 16 * d + 8);
            const int h5 = __builtin_amdgcn_readlane(hpki, 16 * d + 10);
            const int h6 = __builtin_amdgcn_readlane(hpki, 16 * d + 12);
            const int h7 = __builtin_amdgcn_readlane(hpki, 16 * d + 14);
            r0 = __builtin_amdgcn_fdot2(__builtin_bit_cast(half2v, h0),
                                        __builtin_bit_cast(half2v, apk[8*d+0]), r0, false);
            r1 = __builtin_amdgcn_fdot2(__builtin_bit_cast(half2v, h1),
                                        __builtin_bit_cast(half2v, apk[8*d+1]), r1, false);
            r2 = __builtin_amdgcn_fdot2(__builtin_bit_cast(half2v, h2),
                                        __builtin_bit_cast(half2v, apk[8*d+2]), r2, false);
            r3 = __builtin_amdgcn_fdot2(__builtin_bit_cast(half2v, h3),
                                        __builtin_bit_cast(half2v, apk[8*d+3]), r3, false);
            r4 = __builtin_amdgcn_fdot2(__builtin_bit_cast(half2v, h4),
                                        __builtin_bit_cast(half2v, apk[8*d+4]), r4, false);
            r5 = __builtin_amdgcn_fdot2(__builtin_bit_cast(half2v, h5),
                                        __builtin_bit_cast(half2v, apk[8*d+5]), r5, false);
            r6 = __builtin_amdgcn_fdot2(__builtin_bit_cast(half2v, h6),
                                        __builtin_bit_cast(half2v, apk[8*d+6]), r6, false);
            r7 = __builtin_amdgcn_fdot2(__builtin_bit_cast(half2v, h7),
                                        __builtin_bit_cast(half2v, apk[8*d+7]), r7, false);
        }
        const float mv = ((r0 + r1) + (r2 + r3)) + ((r4 + r5) + (r6 + r7));
        const float h = eRs * mv;

        hrow[j * 64 + lane] = h;                 // LDS for the consumer
        if (refill) eR[j] = enext[j * 65];       // E row t+8, in flight ~8 steps
        hprev = h;
    };

    // consumer: process group g-1 (rows (g-1)*8 .. +7) from Hbuf[(g-1)&1]
    auto cgroup = [&](int g) {
        const float* hb = &Hbuf[(g - 1) & 1][0][0];
        float* orow = op + (size_t)(g - 1) * 8 * 65;
        #pragma unroll
        for (int j = 0; j < 8; ++j) {
            const float hl = hb[j * 64 + lane];
            const float S  = wave64_sum_sgpr(hl);
            const unsigned h0 = __builtin_amdgcn_readfirstlane(__float_as_uint(hl));
            Esum += exPrevC - 127;               // Esum_tau (row 0: +0)
            int ex = (int)((h0 >> 23) & 255u);
            exPrevC = ex < 1 ? 1 : (ex > 253 ? 253 : ex);
            const float r = __builtin_amdgcn_rcpf(S);
            orow[j * 65 + lane] = hl * r;
            if (lane == 0) orow[j * 65 + 64] = __logf(S) + (float)Esum * LN2F;
        }
    };

    // ---- iteration g = 0 (peeled: producer does rows 1..7 of group 0) ----
    BAR();
    if (w == 0) {
        const float* enext = op + (size_t)8 * 65 + lane;   // rows 8..15
        float* hrow = &Hbuf[0][0][0];
        #pragma unroll
        for (int j = 1; j < 8; ++j) pbody(j, enext, hrow, true);
    }

    // ---- iterations g = 1 .. 128 ----
    for (int g = 1; g < 129; ++g) {
        BAR();
        if (w == 0) {
            if (g < 128) {
                const float* enext = op + ((size_t)g * 8 + 8) * 65 + lane;
                float* hrow = &Hbuf[g & 1][0][0];
                const bool refill = (g < 127);
                #pragma unroll
                for (int j = 0; j < 8; ++j) pbody(j, enext, hrow, refill);
            }
        } else {
            cgroup(g);
        }
    }
}

// ---------------------------------------------------------------------------
extern "C" void kernel_launch(void* const* d_in, const int* in_sizes, int n_in,
                              void* d_out, int out_size, void* d_ws, size_t ws_size,
                              hipStream_t stream) {
    const float* inputs = (const float*)d_in[0];  // [512,1024,32]
    const float* em     = (const float*)d_in[1];  // [64,32]
    const float* tr     = (const float*)d_in[2];  // [64,64]
    const float* ini    = (const float*)d_in[3];  // [64]
    float* out = (float*)d_out;                   // [512,1024,65]
    float* ws  = (float*)d_ws;                    // 6208 floats used

    hmm_prep<<<1, 64, 0, stream>>>(em, tr, ini, ws);
    hmm_emit<<<BATCH * (TT / 32), 256, 0, stream>>>(inputs, ws, out);
    hmm_scan<<<BATCH, 128, 0, stream>>>(ws, out);
}

// Round 9
// 216.969 us; speedup vs baseline: 1.7183x; 1.7183x over previous
//
#include <hip/hip_runtime.h>

#define BATCH 512
#define TT    1024
#define NST   64
#define NSYM  32
#define NCH   16      // chunks per chain
#define CLEN  64      // TT / NCH
#define WARM  16      // warmup steps (direction converges ~0.16^16)
#define LN2F  0.69314718055994530942f
#define WS_STATS 6400 // float offset of per-(chain,chunk) {Lstart, Lend} pairs

typedef _Float16 half2v __attribute__((ext_vector_type(2)));

// ---------------------------------------------------------------------------
// Wave64 sum reduction on the VALU only (DPP row ops). Total -> lane63 -> SGPR.
// ---------------------------------------------------------------------------
template <int CTRL>
__device__ __forceinline__ float dpp_add(float x) {
    int y = __builtin_amdgcn_update_dpp(0, __float_as_int(x), CTRL, 0xf, 0xf, true);
    return x + __int_as_float(y);
}
__device__ __forceinline__ float wave64_sum_sgpr(float x) {
    x = dpp_add<0x111>(x);   // row_shr:1
    x = dpp_add<0x112>(x);   // row_shr:2
    x = dpp_add<0x114>(x);   // row_shr:4
    x = dpp_add<0x118>(x);   // row_shr:8
    x = dpp_add<0x142>(x);   // row_bcast:15
    x = dpp_add<0x143>(x);   // row_bcast:31 -> lane63 = total
    return __int_as_float(__builtin_amdgcn_readlane(__float_as_int(x), 63));
}

// ---------------------------------------------------------------------------
// Prep: softmax(transition) -> ws[0..4095]   (A[i][j], row-major)
//       softmax(emission)   -> ws[4096..6143] (B[n][s], row-major)
//       softmax(init)       -> ws[6144..6207] (I[n])
// ---------------------------------------------------------------------------
__global__ __launch_bounds__(64) void hmm_prep(
    const float* __restrict__ em, const float* __restrict__ tr,
    const float* __restrict__ ini, float* __restrict__ ws)
{
    const int n = threadIdx.x;

    {
        float a[64];
        float m = -1e30f;
        #pragma unroll
        for (int j = 0; j < 64; ++j) { a[j] = tr[n * 64 + j]; m = fmaxf(m, a[j]); }
        float s = 0.f;
        #pragma unroll
        for (int j = 0; j < 64; ++j) { a[j] = __expf(a[j] - m); s += a[j]; }
        const float inv = 1.f / s;
        #pragma unroll
        for (int j = 0; j < 64; ++j) ws[n * 64 + j] = a[j] * inv;
    }
    {
        float bv[32];
        float m = -1e30f;
        #pragma unroll
        for (int j = 0; j < 32; ++j) { bv[j] = em[n * 32 + j]; m = fmaxf(m, bv[j]); }
        float s = 0.f;
        #pragma unroll
        for (int j = 0; j < 32; ++j) { bv[j] = __expf(bv[j] - m); s += bv[j]; }
        const float inv = 1.f / s;
        #pragma unroll
        for (int j = 0; j < 32; ++j) ws[4096 + n * 32 + j] = bv[j] * inv;
    }
    {
        float v = ini[n];
        float m = v;
        #pragma unroll
        for (int off = 32; off; off >>= 1) m = fmaxf(m, __shfl_xor(m, off, 64));
        const float e = __expf(v - m);
        float s = e;
        #pragma unroll
        for (int off = 32; off; off >>= 1) s += __shfl_xor(s, off, 64);
        ws[6144 + n] = e / s;
    }
}

// ---------------------------------------------------------------------------
// Chunked scan: 8192 independent wave-tasks = (chain b, chunk c), 4 per block.
//  Chunk c owns output rows [c*64, c*64+63].  c>0 warms up 16+1 steps from the
//  uniform vector (direction forgets the start: |lambda2|~0.16/step).
//  Per step: inline emission dot (wave-uniform x row -> scalar loads, 32 FMA),
//  readlane+fdot2 matvec vs f16-packed A columns, power-of-2 rescale from the
//  stale exponent of h[0], DPP sum + delayed f/raw-ll writes.
//  ll slots get LOCAL L_t = log(S_t)+Esum*ln2; per-chunk {Lstart,Lend} go to
//  ws; hmm_fix chains them exactly (telescoping) afterwards.
// ---------------------------------------------------------------------------
__global__ __launch_bounds__(256) void hmm_scan(
    const float* __restrict__ inputs, const float* __restrict__ ws,
    float* __restrict__ out)
{
    const int lane = threadIdx.x & 63;
    const int task = blockIdx.x * 4 + (threadIdx.x >> 6);
    const int b    = task >> 4;
    const int c    = task & (NCH - 1);
    const int t0   = c * CLEN;

#if __has_builtin(__builtin_amdgcn_fdot2)
    // packed A columns: apk[d] = (A[2d][lane], A[2d+1][lane]) as half2
    int apk[32];
    #pragma unroll
    for (int d = 0; d < 32; ++d) {
        const float a0 = ws[(2 * d)     * 64 + lane];
        const float a1 = ws[(2 * d + 1) * 64 + lane];
        apk[d] = __builtin_bit_cast(int, __builtin_amdgcn_cvt_pkrtz(a0, a1));
    }
    #pragma unroll
    for (int d = 0; d < 32; ++d) asm volatile("" : "+v"(apk[d]));
#else
    float Acol[64];
    #pragma unroll
    for (int i = 0; i < 64; ++i) Acol[i] = ws[i * 64 + lane];
    #pragma unroll
    for (int i = 0; i < 64; ++i) asm volatile("" : "+v"(Acol[i]));
#endif
    float Brow[32];
    {
        const float4* B4 = reinterpret_cast<const float4*>(ws + 4096 + lane * 32);
        #pragma unroll
        for (int i = 0; i < 8; ++i) {
            float4 v = B4[i];
            Brow[4*i+0] = v.x; Brow[4*i+1] = v.y;
            Brow[4*i+2] = v.z; Brow[4*i+3] = v.w;
        }
    }

    const float* __restrict__ xp = inputs + (size_t)b * (TT * NSYM);
    float* __restrict__ op       = out    + (size_t)b * (TT * 65);

    float hprev;
    int   Esum   = 0;
    float Lstart = 0.f;

    // one recurrence step: h_t from h_{t-1}; optionally write row t-1
    auto do_step = [&](int t, bool writeOut) {
        // ---- inline emission dot: x row t is wave-uniform -> scalar loads ----
        const float* __restrict__ xr = xp + (size_t)t * NSYM;
        float e0 = 0.f, e1 = 0.f, e2 = 0.f, e3 = 0.f;
        #pragma unroll
        for (int q = 0; q < 8; ++q) {
            e0 = fmaf(xr[4*q+0], Brow[4*q+0], e0);
            e1 = fmaf(xr[4*q+1], Brow[4*q+1], e1);
            e2 = fmaf(xr[4*q+2], Brow[4*q+2], e2);
            e3 = fmaf(xr[4*q+3], Brow[4*q+3], e3);
        }
        const float e = (e0 + e1) + (e2 + e3);

        // ---- power-of-2 rescale from stale exponent of h_{t-1}[0] (SALU) ----
        const unsigned bits = __builtin_amdgcn_readfirstlane(__float_as_uint(hprev));
        int ex = (int)((bits >> 23) & 255u);
        ex = ex < 1 ? 1 : (ex > 253 ? 253 : ex);
        const float sc = __uint_as_float((unsigned)(254 - ex) << 23);   // 2^(127-ex)
        const int EsumPrev = Esum;
        Esum += ex - 127;
        const float eRs = e * sc;

        // ---- delayed-output reduce (only when writing) ----
        float S = 0.f;
        if (writeOut) S = wave64_sum_sgpr(hprev);

        // ---- matvec via readlane broadcast ----
#if __has_builtin(__builtin_amdgcn_fdot2)
        const int hnb = __builtin_amdgcn_update_dpp(
            0, __float_as_int(hprev), 0x101, 0xf, 0xf, true);   // row_shl:1
        const int hpki = __builtin_bit_cast(int,
            __builtin_amdgcn_cvt_pkrtz(hprev, __int_as_float(hnb)));

        float r0 = 0.f, r1 = 0.f, r2 = 0.f, r3 = 0.f;
        float r4 = 0.f, r5 = 0.f, r6 = 0.f, r7 = 0.f;
        #pragma unroll
        for (int d = 0; d < 4; ++d) {
            const int h0 = __builtin_amdgcn_readlane(hpki, 16 * d + 0);
            const int h1 = __builtin_amdgcn_readlane(hpki, 16 * d + 2);
            const int h2 = __builtin_amdgcn_readlane(hpki, 16 * d + 4);
            const int h3 = __builtin_amdgcn_readlane(hpki, 16 * d + 6);
            const int h4 = __builtin_amdgcn_readlane(hpki, 16 * d + 8);
            const int h5 = __builtin_amdgcn_readlane(hpki, 16 * d + 10);
            const int h6 = __builtin_amdgcn_readlane(hpki, 16 * d + 12);
            const int h7 = __builtin_amdgcn_readlane(hpki, 16 * d + 14);
            r0 = __builtin_amdgcn_fdot2(__builtin_bit_cast(half2v, h0),
                                        __builtin_bit_cast(half2v, apk[8*d+0]), r0, false);
            r1 = __builtin_amdgcn_fdot2(__builtin_bit_cast(half2v, h1),
                                        __builtin_bit_cast(half2v, apk[8*d+1]), r1, false);
            r2 = __builtin_amdgcn_fdot2(__builtin_bit_cast(half2v, h2),
                                        __builtin_bit_cast(half2v, apk[8*d+2]), r2, false);
            r3 = __builtin_amdgcn_fdot2(__builtin_bit_cast(half2v, h3),
                                        __builtin_bit_cast(half2v, apk[8*d+3]), r3, false);
            r4 = __builtin_amdgcn_fdot2(__builtin_bit_cast(half2v, h4),
                                        __builtin_bit_cast(half2v, apk[8*d+4]), r4, false);
            r5 = __builtin_amdgcn_fdot2(__builtin_bit_cast(half2v, h5),
                                        __builtin_bit_cast(half2v, apk[8*d+5]), r5, false);
            r6 = __builtin_amdgcn_fdot2(__builtin_bit_cast(half2v, h6),
                                        __builtin_bit_cast(half2v, apk[8*d+6]), r6, false);
            r7 = __builtin_amdgcn_fdot2(__builtin_bit_cast(half2v, h7),
                                        __builtin_bit_cast(half2v, apk[8*d+7]), r7, false);
        }
        const float mv = ((r0 + r1) + (r2 + r3)) + ((r4 + r5) + (r6 + r7));
#else
        float r0 = 0.f, r1 = 0.f, r2 = 0.f, r3 = 0.f;
        float r4 = 0.f, r5 = 0.f, r6 = 0.f, r7 = 0.f;
        const int hbits = __float_as_int(hprev);
        #pragma unroll
        for (int d = 0; d < 8; ++d) {
            r0 = fmaf(__int_as_float(__builtin_amdgcn_readlane(hbits, 8*d+0)), Acol[8*d+0], r0);
            r1 = fmaf(__int_as_float(__builtin_amdgcn_readlane(hbits, 8*d+1)), Acol[8*d+1], r1);
            r2 = fmaf(__int_as_float(__builtin_amdgcn_readlane(hbits, 8*d+2)), Acol[8*d+2], r2);
            r3 = fmaf(__int_as_float(__builtin_amdgcn_readlane(hbits, 8*d+3)), Acol[8*d+3], r3);
            r4 = fmaf(__int_as_float(__builtin_amdgcn_readlane(hbits, 8*d+4)), Acol[8*d+4], r4);
            r5 = fmaf(__int_as_float(__builtin_amdgcn_readlane(hbits, 8*d+5)), Acol[8*d+5], r5);
            r6 = fmaf(__int_as_float(__builtin_amdgcn_readlane(hbits, 8*d+6)), Acol[8*d+6], r6);
            r7 = fmaf(__int_as_float(__builtin_amdgcn_readlane(hbits, 8*d+7)), Acol[8*d+7], r7);
        }
        const float mv = ((r0 + r1) + (r2 + r3)) + ((r4 + r5) + (r6 + r7));
#endif
        const float h = eRs * mv;

        if (writeOut) {
            const float r = __builtin_amdgcn_rcpf(S);
            op[(size_t)(t - 1) * 65 + lane] = hprev * r;
            if (lane == 0)
                op[(size_t)(t - 1) * 65 + 64] = __logf(S) + (float)EsumPrev * LN2F;
        }
        hprev = h;
    };

    if (c == 0) {
        // exact start: h0 = e0 o I  (sc=1, Esum=0, Lstart=0)
        const float* __restrict__ xr = xp;
        float e0 = 0.f, e1 = 0.f, e2 = 0.f, e3 = 0.f;
        #pragma unroll
        for (int q = 0; q < 8; ++q) {
            e0 = fmaf(xr[4*q+0], Brow[4*q+0], e0);
            e1 = fmaf(xr[4*q+1], Brow[4*q+1], e1);
            e2 = fmaf(xr[4*q+2], Brow[4*q+2], e2);
            e3 = fmaf(xr[4*q+3], Brow[4*q+3], e3);
        }
        hprev = ((e0 + e1) + (e2 + e3)) * ws[6144 + lane];
        Lstart = 0.f;
    } else {
        // warmup from the uniform direction; no outputs
        hprev = 1.0f;
        for (int t = t0 - WARM; t < t0; ++t) do_step(t, false);
        Lstart = __logf(wave64_sum_sgpr(hprev)) + (float)Esum * LN2F;  // L_{t0-1}
        do_step(t0, false);   // silent: h_{t0}  (row t0-1 belongs to chunk c-1)
    }

    // main: 63 steps with delayed outputs for rows t0 .. t0+62
    #pragma unroll 2
    for (int k = 1; k < CLEN; ++k) do_step(t0 + k, true);

    // epilogue: row t0+63 + per-chunk stats
    {
        const float S = wave64_sum_sgpr(hprev);
        const float r = __builtin_amdgcn_rcpf(S);
        const float Lend = __logf(S) + (float)Esum * LN2F;
        op[(size_t)(t0 + CLEN - 1) * 65 + lane] = hprev * r;
        if (lane == 0) {
            op[(size_t)(t0 + CLEN - 1) * 65 + 64] = Lend;
            float* st = (float*)ws + WS_STATS + (size_t)(b * NCH + c) * 2;
            st[0] = Lstart;
            st[1] = Lend;
        }
    }
}

// ---------------------------------------------------------------------------
// Fixup: per chain, exclusive prefix over chunk deltas D_c = Lend_c - Lstart_c,
// then ll[t] += O_{t/64} - Lstart_{t/64}.  (chunk 0: O=0, Lstart=0 -> +0)
// ---------------------------------------------------------------------------
__global__ __launch_bounds__(64) void hmm_fix(
    const float* __restrict__ ws, float* __restrict__ out)
{
    const int b    = blockIdx.x;
    const int lane = threadIdx.x;

    const float* st = ws + WS_STATS + (size_t)b * NCH * 2;
    float Ls = 0.f, D = 0.f;
    if (lane < NCH) {
        Ls = st[lane * 2];
        D  = st[lane * 2 + 1] - Ls;
    }
    // exclusive prefix O_c = sum_{j<c} D_j  (16 lanes, readlane loop)
    float O = 0.f;
    #pragma unroll
    for (int j = 0; j < NCH - 1; ++j) {
        const float Dj = __int_as_float(
            __builtin_amdgcn_readlane(__float_as_int(D), j));
        if (lane > j) O += Dj;
    }
    const float offs = O - Ls;

    float* __restrict__ op = out + (size_t)b * (TT * 65);
    #pragma unroll
    for (int k = 0; k < NCH; ++k) {
        const float offk = __int_as_float(
            __builtin_amdgcn_readlane(__float_as_int(offs), k));
        const size_t idx = (size_t)(k * 64 + lane) * 65 + 64;
        op[idx] += offk;
    }
}

// ---------------------------------------------------------------------------
extern "C" void kernel_launch(void* const* d_in, const int* in_sizes, int n_in,
                              void* d_out, int out_size, void* d_ws, size_t ws_size,
                              hipStream_t stream) {
    const float* inputs = (const float*)d_in[0];  // [512,1024,32]
    const float* em     = (const float*)d_in[1];  // [64,32]
    const float* tr     = (const float*)d_in[2];  // [64,64]
    const float* ini    = (const float*)d_in[3];  // [64]
    float* out = (float*)d_out;                   // [512,1024,65]
    float* ws  = (float*)d_ws;                    // prep 6208 + stats 16384 floats

    hmm_prep<<<1, 64, 0, stream>>>(em, tr, ini, ws);
    hmm_scan<<<(BATCH * NCH) / 4, 256, 0, stream>>>(inputs, ws, out);
    hmm_fix<<<BATCH, 64, 0, stream>>>(ws, out);
}

// Round 11
// 65.600 us; speedup vs baseline: 5.6831x; 3.3075x over previous
//
#include <hip/hip_runtime.h>

#define BATCH 512
#define TT    1024
#define NST   64
#define NSYM  32
#define NCH   16      // chunks per chain (= MFMA N dimension)
#define CLEN  64      // TT / NCH
#define WARM  16      // warmup steps
#define LN2F  0.69314718055994530942f

#define AP_MV    6400   // dword offset: packed matvec A-frags  [4mt][2kc][64][4]
#define AP_EM    8448   // dword offset: packed emission A-frags [4mt][64][4]
#define WS_STATS 9472   // float offset: per-(chain,chunk) {Lstart, Lend}

typedef _Float16 f16x8 __attribute__((ext_vector_type(8)));
typedef float    f32x4 __attribute__((ext_vector_type(4)));

#define MFMA_F16(a,b,c) __builtin_amdgcn_mfma_f32_16x16x32_f16(a,b,c,0,0,0)

// cvt_pkrtz returns __fp16 ext_vector(2); bit-cast through unsigned (same size).
__device__ __forceinline__ unsigned pkrtz_u(float a, float b) {
    return __builtin_bit_cast(unsigned, __builtin_amdgcn_cvt_pkrtz(a, b));
}

// slot(g, r) -> k within a K=32 chunk.  Chosen to match the D-layout
// (row = 4g + reg), so D of step t IS the B-operand of step t+1 per-lane.
// Correct for ANY true hw map as long as A and B share it (k-sum is
// permutation-invariant; A is packed with this same sigma in prep).
__device__ __forceinline__ int sigma_k(int g, int r) {
    return (r < 4) ? (4 * g + r) : (16 + 4 * g + (r - 4));
}

__device__ __forceinline__ f16x8 pk8(float a0, float a1, float a2, float a3,
                                     float a4, float a5, float a6, float a7) {
    union U { unsigned u[4]; f16x8 v; } u;
    u.u[0] = pkrtz_u(a0, a1);
    u.u[1] = pkrtz_u(a2, a3);
    u.u[2] = pkrtz_u(a4, a5);
    u.u[3] = pkrtz_u(a6, a7);
    return u.v;
}

// ---------------------------------------------------------------------------
// Prep.  Phase 1: softmaxes -> ws[0..6207] (A rows, B rows, I).
// Phase 2 (after barrier): pack A^T and Bem into f16 MFMA fragments using
// sigma_k, so the scan loads operand registers directly.
// ---------------------------------------------------------------------------
__global__ __launch_bounds__(64) void hmm_prep(
    const float* __restrict__ em, const float* __restrict__ tr,
    const float* __restrict__ ini, float* __restrict__ ws)
{
    const int n = threadIdx.x;

    {
        float a[64];
        float m = -1e30f;
        #pragma unroll
        for (int j = 0; j < 64; ++j) { a[j] = tr[n * 64 + j]; m = fmaxf(m, a[j]); }
        float s = 0.f;
        #pragma unroll
        for (int j = 0; j < 64; ++j) { a[j] = __expf(a[j] - m); s += a[j]; }
        const float inv = 1.f / s;
        #pragma unroll
        for (int j = 0; j < 64; ++j) ws[n * 64 + j] = a[j] * inv;
    }
    {
        float bv[32];
        float m = -1e30f;
        #pragma unroll
        for (int j = 0; j < 32; ++j) { bv[j] = em[n * 32 + j]; m = fmaxf(m, bv[j]); }
        float s = 0.f;
        #pragma unroll
        for (int j = 0; j < 32; ++j) { bv[j] = __expf(bv[j] - m); s += bv[j]; }
        const float inv = 1.f / s;
        #pragma unroll
        for (int j = 0; j < 32; ++j) ws[4096 + n * 32 + j] = bv[j] * inv;
    }
    {
        float v = ini[n];
        float m = v;
        #pragma unroll
        for (int off = 32; off; off >>= 1) m = fmaxf(m, __shfl_xor(m, off, 64));
        const float e = __expf(v - m);
        float s = e;
        #pragma unroll
        for (int off = 32; off; off >>= 1) s += __shfl_xor(s, off, 64);
        ws[6144 + n] = e / s;
    }

    __syncthreads();   // global writes visible within the block

    // Phase 2: fragment packing (thread n = lane n of the future scan wave)
    const int g   = n >> 4;
    const int cl  = n & 15;
    unsigned* wsu = (unsigned*)ws;

    #pragma unroll
    for (int mt = 0; mt < 4; ++mt) {
        // matvec A-op: A_op[m][k] = Asm[k][m]  (mv = A^T h)
        #pragma unroll
        for (int kc = 0; kc < 2; ++kc) {
            #pragma unroll
            for (int p = 0; p < 4; ++p) {
                const int k0 = sigma_k(g, 2 * p);
                const int k1 = sigma_k(g, 2 * p + 1);
                const int m  = 16 * mt + cl;
                const float a0 = ws[(32 * kc + k0) * 64 + m];
                const float a1 = ws[(32 * kc + k1) * 64 + m];
                wsu[AP_MV + ((mt * 2 + kc) * 64 + n) * 4 + p] = pkrtz_u(a0, a1);
            }
        }
        // emission A-op: A_op[state][sym] = Bsm[state][sym]
        #pragma unroll
        for (int p = 0; p < 4; ++p) {
            const int k0 = sigma_k(g, 2 * p);
            const int k1 = sigma_k(g, 2 * p + 1);
            const int st = 16 * mt + cl;
            const float b0 = ws[4096 + st * 32 + k0];
            const float b1 = ws[4096 + st * 32 + k1];
            wsu[AP_EM + (mt * 64 + n) * 4 + p] = pkrtz_u(b0, b1);
        }
    }
}

// ---------------------------------------------------------------------------
// MFMA scan: one wave per CHAIN, the 16 MFMA columns = the chain's 16 chunks.
//  Per step (advances all 16 chunks one t):
//   E  = Bem(64x32) @ x(32x16)      4 MFMAs  (x rows loaded per-lane, f16)
//   mv = A^T(64x64) @ h(64x16)      8 MFMAs  (h packed from D-layout, per-lane)
//   h  = (E * sc) o mv              sc = exact power of 2 from the exponent of
//                                   a readlane proxy (col 15, never reset)
//  Outputs delayed one step: f = h/S (S via 15-add + 2 shfl_xor butterfly,
//  off the h->h path), ll = log S + Esum*ln2 (local; telescoped by hmm_fix).
//  Warmup 16 steps from h=1 (chunk-boundary forgetting, proven R9);
//  col 0 restarted exactly with E0 o I after the silent k=0 step.
// ---------------------------------------------------------------------------
__global__ __launch_bounds__(64, 1) void hmm_scan(
    const float* __restrict__ inputs, float* __restrict__ ws,
    float* __restrict__ out)
{
    const int lane = threadIdx.x;
    const int col  = lane & 15;    // task/chunk = MFMA column
    const int g    = lane >> 4;
    const int b    = blockIdx.x;

    // operand fragments (invariant)
    f16x8 Amv[4][2], Aem[4];
    {
        const int4* mvp = (const int4*)((const unsigned*)ws + AP_MV);
        #pragma unroll
        for (int mt = 0; mt < 4; ++mt)
            #pragma unroll
            for (int kc = 0; kc < 2; ++kc)
                Amv[mt][kc] = __builtin_bit_cast(f16x8, mvp[(mt * 2 + kc) * 64 + lane]);
        const int4* emp = (const int4*)((const unsigned*)ws + AP_EM);
        #pragma unroll
        for (int mt = 0; mt < 4; ++mt)
            Aem[mt] = __builtin_bit_cast(f16x8, emp[mt * 64 + lane]);
    }

    const float* __restrict__ xp = inputs + (size_t)b * (TT * NSYM);
    float* __restrict__ op       = out    + (size_t)b * (TT * 65);

    // x prefetch ring, depth 4 (per lane: its column's row, two float4 halves)
    float4 rga[4], rgb[4];
    auto loadx = [&](int k, int s) {
        int t = col * CLEN + k;
        t = t < 0 ? 0 : t;
        t = t > TT - 1 ? TT - 1 : t;
        const float* row = xp + (size_t)t * NSYM;
        rga[s] = *(const float4*)(row + 4 * g);
        rgb[s] = *(const float4*)(row + 16 + 4 * g);
    };

    // h in D layout: hD[mt][r] = h[state = 16*mt + 4*g + r][task col]
    float hD[4][4];
    #pragma unroll
    for (int mt = 0; mt < 4; ++mt)
        #pragma unroll
        for (int r = 0; r < 4; ++r) hD[mt][r] = 1.0f;
    int Esum = 0;

    const f32x4 z4 = {0.f, 0.f, 0.f, 0.f};

    auto step = [&](int k, int s, bool store_) {
        // ---- delayed outputs for row t-1 (uses hD = h_{t-1}, pre-update Esum)
        if (store_) {
            float p = 0.f;
            #pragma unroll
            for (int mt = 0; mt < 4; ++mt)
                #pragma unroll
                for (int r = 0; r < 4; ++r) p += hD[mt][r];
            p += __shfl_xor(p, 16, 64);
            p += __shfl_xor(p, 32, 64);          // column total in all 4 g-lanes
            const float rS = __builtin_amdgcn_rcpf(p);
            float* rowp = op + (size_t)(col * CLEN + k - 1) * 65;
            #pragma unroll
            for (int mt = 0; mt < 4; ++mt)
                #pragma unroll
                for (int r = 0; r < 4; ++r)
                    rowp[16 * mt + 4 * g + r] = hD[mt][r] * rS;
            if (g == 0) rowp[64] = __logf(p) + (float)Esum * LN2F;
        }
        // ---- power-of-2 rescale; proxy = state 0 of col 15 (never reset)
        const int pb = __builtin_amdgcn_readlane(__float_as_int(hD[0][0]), 15);
        int ex = (pb >> 23) & 255;
        ex = ex < 1 ? 1 : (ex > 253 ? 253 : ex);
        const float sc = __uint_as_float((unsigned)(254 - ex) << 23);  // 2^(127-ex)
        Esum += ex - 127;
        // ---- emission MFMA
        const f16x8 bx = pk8(rga[s].x, rga[s].y, rga[s].z, rga[s].w,
                             rgb[s].x, rgb[s].y, rgb[s].z, rgb[s].w);
        f32x4 E[4];
        #pragma unroll
        for (int mt = 0; mt < 4; ++mt) E[mt] = MFMA_F16(Aem[mt], bx, z4);
        // ---- matvec MFMA (B operand = repacked hD, zero cross-lane)
        const f16x8 bh0 = pk8(hD[0][0], hD[0][1], hD[0][2], hD[0][3],
                              hD[1][0], hD[1][1], hD[1][2], hD[1][3]);
        const f16x8 bh1 = pk8(hD[2][0], hD[2][1], hD[2][2], hD[2][3],
                              hD[3][0], hD[3][1], hD[3][2], hD[3][3]);
        f32x4 mv[4];
        #pragma unroll
        for (int mt = 0; mt < 4; ++mt) {
            mv[mt] = MFMA_F16(Amv[mt][0], bh0, z4);
            mv[mt] = MFMA_F16(Amv[mt][1], bh1, mv[mt]);
        }
        // ---- h update
        #pragma unroll
        for (int mt = 0; mt < 4; ++mt)
            #pragma unroll
            for (int r = 0; r < 4; ++r)
                hD[mt][r] = (E[mt][r] * sc) * mv[mt][r];
        // ---- refill ring
        loadx(k + 4, s);
    };

    // prologue: ring k = -16..-13
    #pragma unroll
    for (int s = 0; s < 4; ++s) loadx(-WARM + s, s);

    // warmup k = -16..-1 (no outputs; col 0 clamps to row 0 = garbage chain)
    for (int kk = -WARM; kk < 0; kk += 4) {
        #pragma unroll
        for (int s = 0; s < 4; ++s) step(kk + s, s, false);
    }

    // Lstart (state at t0-1), before the silent step
    float Lstart;
    {
        float p = 0.f;
        #pragma unroll
        for (int mt = 0; mt < 4; ++mt)
            #pragma unroll
            for (int r = 0; r < 4; ++r) p += hD[mt][r];
        p += __shfl_xor(p, 16, 64);
        p += __shfl_xor(p, 32, 64);
        Lstart = __logf(p) + (float)Esum * LN2F;
    }
    Lstart = (col == 0) ? 0.f : Lstart;

    // k = 0: silent step (consumes row t0; row t0-1 belongs to chunk c-1)
    step(0, 0, false);

    // col-0 exact restart: h_0 = E_0 o I  (recompute E_0 raw; cheap one-time)
    {
        const float* row = xp + (size_t)(col * CLEN) * NSYM;  // col 0 -> row 0
        const float4 xa = *(const float4*)(row + 4 * g);
        const float4 xb = *(const float4*)(row + 16 + 4 * g);
        const f16x8 bx0 = pk8(xa.x, xa.y, xa.z, xa.w, xb.x, xb.y, xb.z, xb.w);
        #pragma unroll
        for (int mt = 0; mt < 4; ++mt) {
            const f32x4 E0 = MFMA_F16(Aem[mt], bx0, z4);
            const float4 iv = *(const float4*)(ws + 6144 + 16 * mt + 4 * g);
            const float ivv[4] = {iv.x, iv.y, iv.z, iv.w};
            #pragma unroll
            for (int r = 0; r < 4; ++r)
                if (col == 0) hD[mt][r] = E0[r] * ivv[r];
        }
        if (col == 0) Esum = 0;
    }

    // main: k = 1..63, outputs for rows t0..t0+62
    #pragma unroll
    for (int s = 1; s < 4; ++s) step(s, s, true);
    for (int kk = 4; kk <= 60; kk += 4) {
        #pragma unroll
        for (int s = 0; s < 4; ++s) step(kk + s, s, true);
    }

    // epilogue: row t0+63 + per-chunk stats
    {
        float p = 0.f;
        #pragma unroll
        for (int mt = 0; mt < 4; ++mt)
            #pragma unroll
            for (int r = 0; r < 4; ++r) p += hD[mt][r];
        p += __shfl_xor(p, 16, 64);
        p += __shfl_xor(p, 32, 64);
        const float rS = __builtin_amdgcn_rcpf(p);
        float* rowp = op + (size_t)(col * CLEN + 63) * 65;
        #pragma unroll
        for (int mt = 0; mt < 4; ++mt)
            #pragma unroll
            for (int r = 0; r < 4; ++r)
                rowp[16 * mt + 4 * g + r] = hD[mt][r] * rS;
        const float Lend = __logf(p) + (float)Esum * LN2F;
        if (g == 0) {
            rowp[64] = Lend;
            float* st = ws + WS_STATS + (size_t)(b * NCH + col) * 2;
            st[0] = Lstart;
            st[1] = Lend;
        }
    }
}

// ---------------------------------------------------------------------------
// Fixup: per chain, exclusive prefix over chunk deltas D_c = Lend_c - Lstart_c,
// then ll[t] += O_{t/64} - Lstart_{t/64}.  (chunk 0: O=0, Lstart=0 -> +0)
// ---------------------------------------------------------------------------
__global__ __launch_bounds__(64) void hmm_fix(
    const float* __restrict__ ws, float* __restrict__ out)
{
    const int b    = blockIdx.x;
    const int lane = threadIdx.x;

    const float* st = ws + WS_STATS + (size_t)b * NCH * 2;
    float Ls = 0.f, D = 0.f;
    if (lane < NCH) {
        Ls = st[lane * 2];
        D  = st[lane * 2 + 1] - Ls;
    }
    float O = 0.f;
    #pragma unroll
    for (int j = 0; j < NCH - 1; ++j) {
        const float Dj = __int_as_float(
            __builtin_amdgcn_readlane(__float_as_int(D), j));
        if (lane > j) O += Dj;
    }
    const float offs = O - Ls;

    float* __restrict__ op = out + (size_t)b * (TT * 65);
    #pragma unroll
    for (int k = 0; k < NCH; ++k) {
        const float offk = __int_as_float(
            __builtin_amdgcn_readlane(__float_as_int(offs), k));
        const size_t idx = (size_t)(k * 64 + lane) * 65 + 64;
        op[idx] += offk;
    }
}

// ---------------------------------------------------------------------------
extern "C" void kernel_launch(void* const* d_in, const int* in_sizes, int n_in,
                              void* d_out, int out_size, void* d_ws, size_t ws_size,
                              hipStream_t stream) {
    const float* inputs = (const float*)d_in[0];  // [512,1024,32]
    const float* em     = (const float*)d_in[1];  // [64,32]
    const float* tr     = (const float*)d_in[2];  // [64,64]
    const float* ini    = (const float*)d_in[3];  // [64]
    float* out = (float*)d_out;                   // [512,1024,65]
    float* ws  = (float*)d_ws;                    // ~25856 floats used

    hmm_prep<<<1, 64, 0, stream>>>(em, tr, ini, ws);
    hmm_scan<<<BATCH, 64, 0, stream>>>(inputs, ws, out);
    hmm_fix<<<BATCH, 64, 0, stream>>>(ws, out);
}